// Round 5
// baseline (33.566 us; speedup 1.0000x reference)
//
#include <hip/hip_runtime.h>

#define BB 64
#define SS 512
#define DD 768
#define D4 192   // DD/4
#define BG 4     // b rows per tw block

typedef float v4f __attribute__((ext_vector_type(4)));

// Kernel A: tW[b][d] = sum_k topic[b][k] * W[k][d]
// grid (16, 12), block 256. Each block: 4 b's, 64 consecutive d's (16 float4),
// 16-way k-split (48-long chains). W panel read ONCE per 4 b's (151->38 MB L2).
__global__ void tw_kernel(const float* __restrict__ topic,
                          const float* __restrict__ W,
                          float* __restrict__ tW) {
    __shared__ float t_s[BG][DD];          // 12 KB
    __shared__ float4 red[16][BG][16];     // 16 KB
    const int t  = threadIdx.x;
    const int b0 = blockIdx.x * BG;
    const int d4 = blockIdx.y * 16;        // tile start in float4 units
    const int dl = t & 15;
    const int kg = t >> 4;                 // 0..15

#pragma unroll
    for (int bi = 0; bi < BG; ++bi)
        for (int k = t; k < DD; k += 256) t_s[bi][k] = topic[(b0 + bi) * DD + k];
    __syncthreads();

    const float4* __restrict__ W4 = (const float4*)W;  // [DD][D4]
    const int k0 = kg * 48;
    float4 acc[BG];
#pragma unroll
    for (int bi = 0; bi < BG; ++bi) acc[bi] = make_float4(0.f, 0.f, 0.f, 0.f);

#pragma unroll 8
    for (int k = 0; k < 48; ++k) {
        const float4 w = W4[(size_t)(k0 + k) * D4 + d4 + dl];
#pragma unroll
        for (int bi = 0; bi < BG; ++bi) {
            const float ts = t_s[bi][k0 + k];
            acc[bi].x = fmaf(ts, w.x, acc[bi].x);
            acc[bi].y = fmaf(ts, w.y, acc[bi].y);
            acc[bi].z = fmaf(ts, w.z, acc[bi].z);
            acc[bi].w = fmaf(ts, w.w, acc[bi].w);
        }
    }
#pragma unroll
    for (int bi = 0; bi < BG; ++bi) red[kg][bi][dl] = acc[bi];
    __syncthreads();

    if (t < 64) {
        const int bi = t >> 4, d = t & 15;
        float4 s = red[0][bi][d];
#pragma unroll
        for (int j = 1; j < 16; ++j) {
            const float4 r = red[j][bi][d];
            s.x += r.x; s.y += r.y; s.z += r.z; s.w += r.w;
        }
        ((float4*)tW)[(size_t)(b0 + bi) * D4 + d4 + d] = s;
    }
}

// Kernel B: scores[b][s] = dot(tW[b], seq[b][s]) + bias
// One wave per TWO scores (same b): tW loads amortized, seq nontemporal.
__global__ void score_kernel(const float* __restrict__ tW,
                             const float* __restrict__ seq,
                             const float* __restrict__ bias,
                             float* __restrict__ scores) {
    const int gwid = (int)((blockIdx.x * blockDim.x + threadIdx.x) >> 6);
    const int lane = threadIdx.x & 63;
    const int b = gwid >> 8;            // 256 waves per b
    const int s = (gwid & 255) << 1;    // two consecutive s

    const v4f* sp = (const v4f*)(seq + ((size_t)b * SS + s) * DD);
    const float4* tp = (const float4*)(tW + (size_t)b * DD);

    float a0 = 0.f, a1 = 0.f;
#pragma unroll
    for (int k = 0; k < 3; ++k) {
        const float4 t = tp[lane + k * 64];
        const v4f x0 = __builtin_nontemporal_load(sp + lane + k * 64);
        const v4f x1 = __builtin_nontemporal_load(sp + D4 + lane + k * 64);
        a0 = fmaf(x0.x, t.x, a0);
        a0 = fmaf(x0.y, t.y, a0);
        a0 = fmaf(x0.z, t.z, a0);
        a0 = fmaf(x0.w, t.w, a0);
        a1 = fmaf(x1.x, t.x, a1);
        a1 = fmaf(x1.y, t.y, a1);
        a1 = fmaf(x1.z, t.z, a1);
        a1 = fmaf(x1.w, t.w, a1);
    }
#pragma unroll
    for (int off = 32; off >= 1; off >>= 1) {
        a0 += __shfl_xor(a0, off);
        a1 += __shfl_xor(a1, off);
    }

    if (lane == 0) {
        const float bb = bias[0];
        scores[b * SS + s]     = a0 + bb;
        scores[b * SS + s + 1] = a1 + bb;
    }
}

// Kernel C: beta[b] = softmax(scores[b]) over S. One block of 512 per b.
__global__ void softmax_kernel(const float* __restrict__ scores,
                               float* __restrict__ beta) {
    __shared__ float red[8];
    __shared__ float s_m, s_sum;
    const int b   = blockIdx.x;
    const int tid = threadIdx.x;          // 0..511
    const int wid = tid >> 6, lane = tid & 63;

    const float v = scores[b * SS + tid];

    float m = v;
#pragma unroll
    for (int off = 32; off >= 1; off >>= 1) m = fmaxf(m, __shfl_xor(m, off));
    if (lane == 0) red[wid] = m;
    __syncthreads();
    if (tid == 0) {
        float mm = red[0];
#pragma unroll
        for (int i = 1; i < 8; ++i) mm = fmaxf(mm, red[i]);
        s_m = mm;
    }
    __syncthreads();

    const float e = __expf(v - s_m);
    float sum = e;
#pragma unroll
    for (int off = 32; off >= 1; off >>= 1) sum += __shfl_xor(sum, off);
    if (lane == 0) red[wid] = sum;
    __syncthreads();
    if (tid == 0) {
        float ss = 0.f;
#pragma unroll
        for (int i = 0; i < 8; ++i) ss += red[i];
        s_sum = ss;
    }
    __syncthreads();

    beta[b * SS + tid] = e / s_sum;
}

extern "C" void kernel_launch(void* const* d_in, const int* in_sizes, int n_in,
                              void* d_out, int out_size, void* d_ws, size_t ws_size,
                              hipStream_t stream) {
    const float* topic = (const float*)d_in[0];
    const float* seq   = (const float*)d_in[1];
    const float* W     = (const float*)d_in[2];
    const float* bias  = (const float*)d_in[3];
    float* out = (float*)d_out;

    float* tW     = (float*)d_ws;                 // BB*DD floats
    float* scores = tW + (size_t)BB * DD;         // BB*SS floats

    tw_kernel<<<dim3(BB / BG, 12), 256, 0, stream>>>(topic, W, tW);

    const int total_waves = (BB * SS) / 2;        // one wave per two scores
    const int blocks = (total_waves * 64) / 256;  // 4 waves per block
    score_kernel<<<blocks, 256, 0, stream>>>(tW, seq, bias, scores);

    softmax_kernel<<<BB, 512, 0, stream>>>(scores, out);
}